// Round 7
// baseline (226.120 us; speedup 1.0000x reference)
//
#include <hip/hip_runtime.h>

#define N_NODES 50000
#define N_EDGES 800000
#define D_FEAT 96
#define HOP_NUM 4
#define OUT_STRIDE (HOP_NUM * D_FEAT)
#define SCAN_B 256
#define NBLK_SCAN ((N_NODES + SCAN_B - 1) / SCAN_B)  // 196
#define EB_BLOCKS ((N_EDGES + 255) / 256)            // 3125
#define F2B_VEC (N_NODES * D_FEAT / 4)               // 1.2M float4s
#define F2B_BLOCKS ((F2B_VEC + 255) / 256)           // 4688

struct Edge { int s; float w; };
typedef float f32x4 __attribute__((ext_vector_type(4)));

__device__ __forceinline__ unsigned short f2bf(float x) {
    union { float f; unsigned u; } c; c.f = x;
    unsigned r = (c.u + 0x7FFFu + ((c.u >> 16) & 1u)) >> 16;  // RNE
    return (unsigned short)r;
}
__device__ __forceinline__ float bf2f(unsigned short b) {
    union { unsigned u; float f; } c; c.u = ((unsigned)b) << 16;
    return c.f;
}

// ---------- CSR build (once per launch) ----------

__global__ void zero_deg_kernel(int* __restrict__ deg) {
    int i = blockIdx.x * blockDim.x + threadIdx.x;
    if (i < N_NODES) deg[i] = 0;
}

__global__ void hist_kernel(const int* __restrict__ dst, int* __restrict__ deg) {
    int e = blockIdx.x * blockDim.x + threadIdx.x;
    if (e >= N_EDGES) return;
    atomicAdd(&deg[dst[e]], 1);
}

// Per-block exclusive scan of deg into off (block-local), block totals -> partials.
// Also zeroes the scatter cursor and sets off[N_NODES] (local inclusive of last node).
__global__ void scanA_kernel(const int* __restrict__ deg, int* __restrict__ off,
                             int* __restrict__ partials, int* __restrict__ cursor) {
    int i = blockIdx.x * SCAN_B + threadIdx.x;
    int v = (i < N_NODES) ? deg[i] : 0;
    int lane = threadIdx.x & 63;
    int wid  = threadIdx.x >> 6;
    int x = v;
    #pragma unroll
    for (int o = 1; o < 64; o <<= 1) {
        int y = __shfl_up(x, o, 64);
        if (lane >= o) x += y;
    }
    __shared__ int wtot[SCAN_B / 64];
    if (lane == 63) wtot[wid] = x;
    __syncthreads();
    int wbase = 0;
    #pragma unroll
    for (int w = 0; w < SCAN_B / 64; ++w) wbase += (w < wid) ? wtot[w] : 0;
    if (i < N_NODES) {
        off[i] = wbase + x - v;   // block-local exclusive
        cursor[i] = 0;
    }
    if (i == N_NODES - 1) off[N_NODES] = wbase + x;  // local inclusive at last node
    if (threadIdx.x == SCAN_B - 1) partials[blockIdx.x] = wbase + x;  // block total
}

// Single block scans the 196 block totals (exclusive, in place).
__global__ void scanB_kernel(int* __restrict__ partials) {
    int tid = threadIdx.x;  // 256 threads
    int v = (tid < NBLK_SCAN) ? partials[tid] : 0;
    int lane = tid & 63;
    int wid  = tid >> 6;
    int x = v;
    #pragma unroll
    for (int o = 1; o < 64; o <<= 1) {
        int y = __shfl_up(x, o, 64);
        if (lane >= o) x += y;
    }
    __shared__ int wtot[SCAN_B / 64];
    if (lane == 63) wtot[wid] = x;
    __syncthreads();
    int wbase = 0;
    #pragma unroll
    for (int w = 0; w < SCAN_B / 64; ++w) wbase += (w < wid) ? wtot[w] : 0;
    if (tid < NBLK_SCAN) partials[tid] = wbase + x - v;
}

// Fused: blocks [0, EB_BLOCKS) scatter edges into dst-sorted CSR;
// blocks [EB_BLOCKS, ...) convert f32 features -> bf16 table.
__global__ void scatter_f2bf_kernel(const int* __restrict__ src, const int* __restrict__ dst,
                                    const float* __restrict__ dn,
                                    const int* __restrict__ off, const int* __restrict__ partials,
                                    int* __restrict__ cursor, Edge* __restrict__ edges,
                                    const float* __restrict__ h, unsigned short* __restrict__ tab) {
    int b = blockIdx.x;
    if (b < EB_BLOCKS) {
        int e = b * 256 + threadIdx.x;
        if (e >= N_EDGES) return;
        int t = dst[e];
        int s = src[e];
        float w = dn[s] * dn[t];
        int p = atomicAdd(&cursor[t], 1);
        int idx = off[t] + partials[t >> 8] + p;
        Edge ed; ed.s = s; ed.w = w;
        edges[idx] = ed;
    } else {
        int i = (b - EB_BLOCKS) * 256 + threadIdx.x;
        if (i >= F2B_VEC) return;
        float4 v = ((const float4*)h)[i];
        ushort4 o;
        o.x = f2bf(v.x); o.y = f2bf(v.y); o.z = f2bf(v.z); o.w = f2bf(v.w);
        ((ushort4*)tab)[i] = o;
    }
}

// ---------- fused per-hop SpMM + residual blend (bf16 gather table) ----------
// 32-lane group per dst node; lanes 0..23 own 4 channels (ushort4 = 8 B).
__global__ void spmm_gather_kernel(const unsigned short* __restrict__ tab,
                                   const int* __restrict__ off,
                                   const int* __restrict__ partials,
                                   const Edge* __restrict__ edges,
                                   const float* __restrict__ lr, int hop,
                                   float* __restrict__ out,
                                   unsigned short* __restrict__ tab_next) {
    int gid = (blockIdx.x * blockDim.x + threadIdx.x) >> 5;
    int lane = threadIdx.x & 31;
    if (gid >= N_NODES) return;
    int beg = off[gid] + partials[gid >> 8];
    int end = off[gid + 1] + partials[(gid + 1) >> 8];
    const bool ch = (lane < 24);

    float4 acc = make_float4(0.f, 0.f, 0.f, 0.f);
    for (int b = beg; b < end; b += 32) {
        int m = min(32, end - b);
        int s_l = 0; float w_l = 0.f;
        if (lane < m) {
            Edge ed = edges[b + lane];
            s_l = ed.s; w_l = ed.w;
        }
        int j = 0;
        for (; j + 4 <= m; j += 4) {
            int   s0 = __shfl(s_l, j,     32);
            int   s1 = __shfl(s_l, j + 1, 32);
            int   s2 = __shfl(s_l, j + 2, 32);
            int   s3 = __shfl(s_l, j + 3, 32);
            float w0 = __shfl(w_l, j,     32);
            float w1 = __shfl(w_l, j + 1, 32);
            float w2 = __shfl(w_l, j + 2, 32);
            float w3 = __shfl(w_l, j + 3, 32);
            if (ch) {
                ushort4 u0 = ((const ushort4*)(tab + (long long)s0 * D_FEAT))[lane];
                ushort4 u1 = ((const ushort4*)(tab + (long long)s1 * D_FEAT))[lane];
                ushort4 u2 = ((const ushort4*)(tab + (long long)s2 * D_FEAT))[lane];
                ushort4 u3 = ((const ushort4*)(tab + (long long)s3 * D_FEAT))[lane];
                acc.x = fmaf(bf2f(u0.x), w0, fmaf(bf2f(u1.x), w1, fmaf(bf2f(u2.x), w2, fmaf(bf2f(u3.x), w3, acc.x))));
                acc.y = fmaf(bf2f(u0.y), w0, fmaf(bf2f(u1.y), w1, fmaf(bf2f(u2.y), w2, fmaf(bf2f(u3.y), w3, acc.y))));
                acc.z = fmaf(bf2f(u0.z), w0, fmaf(bf2f(u1.z), w1, fmaf(bf2f(u2.z), w2, fmaf(bf2f(u3.z), w3, acc.z))));
                acc.w = fmaf(bf2f(u0.w), w0, fmaf(bf2f(u1.w), w1, fmaf(bf2f(u2.w), w2, fmaf(bf2f(u3.w), w3, acc.w))));
            }
        }
        for (; j < m; ++j) {
            int   s = __shfl(s_l, j, 32);
            float w = __shfl(w_l, j, 32);
            if (ch) {
                ushort4 u = ((const ushort4*)(tab + (long long)s * D_FEAT))[lane];
                acc.x = fmaf(bf2f(u.x), w, acc.x);
                acc.y = fmaf(bf2f(u.y), w, acc.y);
                acc.z = fmaf(bf2f(u.z), w, acc.z);
                acc.w = fmaf(bf2f(u.w), w, acc.w);
            }
        }
    }

    if (ch) {
        float r = lr[hop];
        ushort4 pu = ((const ushort4*)(tab + (long long)gid * D_FEAT))[lane];
        f32x4 o;
        o.x = acc.x * r + (1.0f - r) * bf2f(pu.x);
        o.y = acc.y * r + (1.0f - r) * bf2f(pu.y);
        o.z = acc.z * r + (1.0f - r) * bf2f(pu.z);
        o.w = acc.w * r + (1.0f - r) * bf2f(pu.w);
        // write-once output: nontemporal to avoid evicting the gather table
        __builtin_nontemporal_store(o, (f32x4*)(out + (long long)gid * OUT_STRIDE) + lane);
        if (tab_next) {
            ushort4 ov;
            ov.x = f2bf(o.x); ov.y = f2bf(o.y); ov.z = f2bf(o.z); ov.w = f2bf(o.w);
            ((ushort4*)(tab_next + (long long)gid * D_FEAT))[lane] = ov;
        }
    }
}

extern "C" void kernel_launch(void* const* d_in, const int* in_sizes, int n_in,
                              void* d_out, int out_size, void* d_ws, size_t ws_size,
                              hipStream_t stream) {
    const float* h   = (const float*)d_in[0];
    const float* dn  = (const float*)d_in[1];
    const int*   src = (const int*)d_in[2];
    const int*   dst = (const int*)d_in[3];
    const float* lr  = (const float*)d_in[4];
    float* out = (float*)d_out;

    // workspace carve-up (16B-aligned chunks first)
    char* base = (char*)d_ws;
    Edge* edges = (Edge*)base;                    base += (size_t)N_EDGES * sizeof(Edge);
    unsigned short* tabA = (unsigned short*)base; base += (size_t)N_NODES * D_FEAT * sizeof(unsigned short);
    unsigned short* tabB = (unsigned short*)base; base += (size_t)N_NODES * D_FEAT * sizeof(unsigned short);
    int* off      = (int*)base;                   base += (N_NODES + 1) * sizeof(int);
    int* deg      = (int*)base;                   base += N_NODES * sizeof(int);
    int* cursor   = (int*)base;                   base += N_NODES * sizeof(int);
    int* partials = (int*)base;                   base += NBLK_SCAN * sizeof(int);

    zero_deg_kernel<<<NBLK_SCAN, SCAN_B, 0, stream>>>(deg);
    hist_kernel<<<EB_BLOCKS, 256, 0, stream>>>(dst, deg);
    scanA_kernel<<<NBLK_SCAN, SCAN_B, 0, stream>>>(deg, off, partials, cursor);
    scanB_kernel<<<1, SCAN_B, 0, stream>>>(partials);
    scatter_f2bf_kernel<<<EB_BLOCKS + F2B_BLOCKS, 256, 0, stream>>>(
        src, dst, dn, off, partials, cursor, edges, h, tabA);

    // 4 fused hops (bf16 ping-pong tables)
    const int GROUPS_PER_BLOCK = 8;  // 256 threads = 8 x 32-lane groups
    const int HB = (N_NODES + GROUPS_PER_BLOCK - 1) / GROUPS_PER_BLOCK;
    unsigned short* cur = tabA;
    unsigned short* nxt = tabB;
    for (int hop = 0; hop < HOP_NUM; ++hop) {
        unsigned short* wr = (hop == HOP_NUM - 1) ? (unsigned short*)nullptr : nxt;
        spmm_gather_kernel<<<HB, 256, 0, stream>>>(cur, off, partials, edges, lr, hop,
                                                   out + hop * D_FEAT, wr);
        unsigned short* t = cur; cur = nxt; nxt = t;
    }
}